// Round 1
// baseline (559.557 us; speedup 1.0000x reference)
//
#include <hip/hip_runtime.h>
#include <float.h>

#define Bc 32
#define Nc 512
#define Dc 128
#define Hc 8
#define DKc 16
#define Ec 128

// ---- detector: is mask stored as 1-byte bool (flag=1) or int32 (flag=0)? ----
__global__ void detect_mask_kernel(const unsigned char* __restrict__ m, int* __restrict__ flag) {
  int t = threadIdx.x;
  int any = 0;
  for (int u = t; u < 16384; u += 256)
    if ((u & 3) != 0 && m[u] != 0) any = 1;
  unsigned long long bal = __ballot(any != 0);
  if ((t & 63) == 0 && bal != 0ULL) atomicOr(flag, 1);
}

// ---- kernel A: QKV projection, Q pre-scaled by 1/sqrt(dk)=0.25 ----
__global__ __launch_bounds__(256) void qkv_proj(
    const float* __restrict__ q,
    const float* __restrict__ Wq, const float* __restrict__ Wk, const float* __restrict__ Wv,
    float* __restrict__ Qp, float* __restrict__ Kp, float* __restrict__ Vp)
{
  __shared__ float qs[2][Dc];
  int blk = blockIdx.x;
  int b = blk / (Nc/2);
  int n0 = (blk - b*(Nc/2)) * 2;
  int t = threadIdx.x;
  int r = t >> 7, c = t & 127;
  qs[r][c] = q[((size_t)b*Nc + n0 + r)*Dc + c];
  __syncthreads();
  int h = c >> 4, k = c & 15;
  const float* wq = Wq + h*Dc*DKc + k;
  const float* wk = Wk + h*Dc*DKc + k;
  const float* wv = Wv + h*Dc*DKc + k;
  float aq = 0.f, ak = 0.f, av = 0.f;
  #pragma unroll 16
  for (int d = 0; d < Dc; ++d) {
    float x = qs[r][d];
    aq = fmaf(x, wq[d*DKc], aq);
    ak = fmaf(x, wk[d*DKc], ak);
    av = fmaf(x, wv[d*DKc], av);
  }
  size_t o = (((size_t)h*Bc + b)*Nc + (n0 + r))*DKc + k;
  Qp[o] = aq * 0.25f;
  Kp[o] = ak;
  Vp[o] = av;
}

// ---- kernel B: fused edge-MLP + masked softmax attention, one block per (b,i) ----
__global__ __launch_bounds__(256) void attn_fused(
    const float* __restrict__ edge, const unsigned char* __restrict__ maskB,
    const int* __restrict__ flag,
    const float* __restrict__ Qp, const float* __restrict__ Kp, const float* __restrict__ Vp,
    const float* __restrict__ Wout,
    const float* __restrict__ mW1, const float* __restrict__ mb1,
    const float* __restrict__ mW2, const float* __restrict__ mb2,
    const float* __restrict__ mW3, const float* __restrict__ mb3,
    float* __restrict__ out)
{
  __shared__ float sc[Hc][Nc];       // 16 KB scores
  __shared__ float qrow[Hc][DKc];
  __shared__ float headout[Hc][DKc];
  __shared__ float wl[448];          // MLP weights: W1[0:16) b1[16:32) W2[32:288) b2[288:304) W3[304:432) b3[432:440)

  int t = threadIdx.x;
  int gid = blockIdx.x;
  int b = gid >> 9;
  int i = gid & (Nc - 1);

  for (int u = t; u < 448; u += 256) {
    float v = 0.f;
    if (u < 16) v = mW1[u];
    else if (u < 32)  v = mb1[u - 16];
    else if (u < 288) v = mW2[u - 32];
    else if (u < 304) v = mb2[u - 288];
    else if (u < 432) v = mW3[u - 304];
    else if (u < 440) v = mb3[u - 432];
    wl[u] = v;
  }
  if (t < 128) {
    int h = t >> 4, k = t & 15;
    qrow[h][k] = Qp[(((size_t)h*Bc + b)*Nc + i)*DKc + k];
  }
  __syncthreads();

  // ---- phase 2: per-thread edge MLP + 8-head QK dots for j0=t, j1=t+256 ----
  {
    int j0 = t, j1 = t + 256;
    size_t base = ((size_t)b*Nc + i)*Nc;
    float e0 = edge[base + j0], e1 = edge[base + j1];
    int m0, m1;
    if (*flag) { m0 = maskB[base + j0]; m1 = maskB[base + j1]; }
    else { const int* mi = (const int*)maskB; m0 = mi[base + j0]; m1 = mi[base + j1]; }

    float h1a[16], h1b[16];
    #pragma unroll
    for (int u = 0; u < 16; ++u) {
      h1a[u] = fmaxf(0.f, fmaf(e0, wl[u], wl[16 + u]));
      h1b[u] = fmaxf(0.f, fmaf(e1, wl[u], wl[16 + u]));
    }
    float h2a[16], h2b[16];
    #pragma unroll
    for (int u = 0; u < 16; ++u) { h2a[u] = wl[288 + u]; h2b[u] = h2a[u]; }
    #pragma unroll
    for (int v = 0; v < 16; ++v) {
      float wa = h1a[v], wb = h1b[v];
      #pragma unroll
      for (int u = 0; u < 16; ++u) {
        float w = wl[32 + v*16 + u];
        h2a[u] = fmaf(wa, w, h2a[u]);
        h2b[u] = fmaf(wb, w, h2b[u]);
      }
    }
    float ba[8], bb[8];
    #pragma unroll
    for (int u = 0; u < 8; ++u) { ba[u] = wl[432 + u]; bb[u] = ba[u]; }
    #pragma unroll
    for (int v = 0; v < 16; ++v) {
      float wa = fmaxf(0.f, h2a[v]), wb = fmaxf(0.f, h2b[v]);
      #pragma unroll
      for (int u = 0; u < 8; ++u) {
        float w = wl[304 + v*8 + u];
        ba[u] = fmaf(wa, w, ba[u]);
        bb[u] = fmaf(wb, w, bb[u]);
      }
    }
    #pragma unroll
    for (int h = 0; h < Hc; ++h) {
      const float4* k0 = (const float4*)(Kp + (((size_t)h*Bc + b)*Nc + j0)*DKc);
      const float4* k1 = (const float4*)(Kp + (((size_t)h*Bc + b)*Nc + j1)*DKc);
      const float4* q4 = (const float4*)(&qrow[h][0]);
      float s0 = ba[h], s1 = bb[h];
      #pragma unroll
      for (int kk = 0; kk < 4; ++kk) {
        float4 qv = q4[kk];
        float4 ka = k0[kk], kb = k1[kk];
        s0 = fmaf(qv.x, ka.x, s0); s0 = fmaf(qv.y, ka.y, s0);
        s0 = fmaf(qv.z, ka.z, s0); s0 = fmaf(qv.w, ka.w, s0);
        s1 = fmaf(qv.x, kb.x, s1); s1 = fmaf(qv.y, kb.y, s1);
        s1 = fmaf(qv.z, kb.z, s1); s1 = fmaf(qv.w, kb.w, s1);
      }
      sc[h][j0] = m0 ? -FLT_MAX : s0;
      sc[h][j1] = m1 ? -FLT_MAX : s1;
    }
  }
  __syncthreads();

  // ---- phase 3: per-wave masked softmax + PV (4 waves x 2 heads) ----
  {
    int w = t >> 6, lane = t & 63;
    #pragma unroll
    for (int hh = 0; hh < 2; ++hh) {
      int h = w*2 + hh;
      float mx = -FLT_MAX;
      #pragma unroll
      for (int j = lane; j < Nc; j += 64) mx = fmaxf(mx, sc[h][j]);
      #pragma unroll
      for (int off = 32; off > 0; off >>= 1) mx = fmaxf(mx, __shfl_xor(mx, off));
      float sum = 0.f;
      #pragma unroll
      for (int j = lane; j < Nc; j += 64) {
        float p = __expf(sc[h][j] - mx);
        sc[h][j] = p;
        sum += p;
      }
      #pragma unroll
      for (int off = 32; off > 0; off >>= 1) sum += __shfl_xor(sum, off);
      float inv = (mx == -FLT_MAX) ? 0.f : 1.f / sum;  // all-masked row -> zeros (ref semantics)
      int k = lane & 15, g = lane >> 4;
      const float* vb = Vp + (((size_t)h*Bc + b)*Nc)*DKc + k;
      float acc = 0.f;
      #pragma unroll 8
      for (int j = g; j < Nc; j += 4) acc = fmaf(sc[h][j], vb[(size_t)j*DKc], acc);
      acc += __shfl_xor(acc, 16);
      acc += __shfl_xor(acc, 32);
      if (lane < 16) headout[h][k] = acc * inv;
    }
  }
  __syncthreads();

  // ---- phase 4: output projection over (h,k) -> e ----
  if (t < Ec) {
    const float4* ho4 = (const float4*)(&headout[0][0]);
    float acc = 0.f;
    #pragma unroll
    for (int u = 0; u < 32; ++u) {
      float4 hv = ho4[u];
      acc = fmaf(hv.x, Wout[(4*u + 0)*Ec + t], acc);
      acc = fmaf(hv.y, Wout[(4*u + 1)*Ec + t], acc);
      acc = fmaf(hv.z, Wout[(4*u + 2)*Ec + t], acc);
      acc = fmaf(hv.w, Wout[(4*u + 3)*Ec + t], acc);
    }
    out[((size_t)b*Nc + i)*Ec + t] = acc;
  }
}

extern "C" void kernel_launch(void* const* d_in, const int* in_sizes, int n_in,
                              void* d_out, int out_size, void* d_ws, size_t ws_size,
                              hipStream_t stream)
{
  const float* q    = (const float*)d_in[0];
  const unsigned char* mask = (const unsigned char*)d_in[1];
  const float* edge = (const float*)d_in[2];
  const float* Wq   = (const float*)d_in[3];
  const float* Wk   = (const float*)d_in[4];
  const float* Wv   = (const float*)d_in[5];
  const float* Wo   = (const float*)d_in[6];
  const float* mW1  = (const float*)d_in[7];
  const float* mb1  = (const float*)d_in[8];
  const float* mW2  = (const float*)d_in[9];
  const float* mb2  = (const float*)d_in[10];
  const float* mW3  = (const float*)d_in[11];
  const float* mb3  = (const float*)d_in[12];
  float* out = (float*)d_out;

  size_t per = (size_t)Hc*Bc*Nc*DKc;       // 2,097,152 floats per matrix
  float* Qp = (float*)d_ws;
  float* Kp = Qp + per;
  float* Vp = Kp + per;
  int* flag = (int*)(Vp + per);            // ~25.2 MB used

  hipMemsetAsync(flag, 0, sizeof(int), stream);
  detect_mask_kernel<<<1, 256, 0, stream>>>(mask, flag);
  qkv_proj<<<dim3(Bc*Nc/2), dim3(256), 0, stream>>>(q, Wq, Wk, Wv, Qp, Kp, Vp);
  attn_fused<<<dim3(Bc*Nc), dim3(256), 0, stream>>>(edge, mask, flag, Qp, Kp, Vp, Wo,
      mW1, mb1, mW2, mb2, mW3, mb3, out);
}

// Round 2
// 156.239 us; speedup vs baseline: 3.5814x; 3.5814x over previous
//
#include <hip/hip_runtime.h>
#include <hip/hip_bf16.h>
#include <float.h>

#define Bc 32
#define Nc 512
#define Dc 128
#define Hc 8
#define DKc 16
#define Ec 128

typedef __attribute__((ext_vector_type(4))) short s16x4;
typedef __attribute__((ext_vector_type(8))) short s16x8;
typedef __attribute__((ext_vector_type(4))) float f32x4;

union BFU { __hip_bfloat16 b; short s; };
static __device__ inline short f2bf(float f) { BFU u; u.b = __float2bfloat16(f); return u.s; }
static __device__ inline s16x4 pack4(float a, float b, float c, float d) {
  s16x4 r; r[0] = f2bf(a); r[1] = f2bf(b); r[2] = f2bf(c); r[3] = f2bf(d); return r;
}

// D = A*B + C for 16x16x16 bf16. A: lane holds A[l&15][(l>>4)*4+i]; B: B[(l>>4)*4+i][l&15];
// C/D: col=l&15, row=(l>>4)*4+reg (m89-verified layout family).
static __device__ inline f32x4 mfma16(s16x4 a, s16x4 b, f32x4 c) {
#if __has_builtin(__builtin_amdgcn_mfma_f32_16x16x16bf16_1k)
  return __builtin_amdgcn_mfma_f32_16x16x16bf16_1k(a, b, c, 0, 0, 0);
#else
  // Fallback: zero-padded K=32 MFMA; redistribute k-elements (4/lane-group -> 8/lane-group).
  int lane = threadIdx.x & 63;
  int g = lane >> 4, base = lane & 15;
  int src0 = (base + 32 * g) & 63;
  int src1 = (base + 32 * g + 16) & 63;
  int ax = ((int*)&a)[0], ay = ((int*)&a)[1];
  int bx = ((int*)&b)[0], by = ((int*)&b)[1];
  int A0 = __shfl(ax, src0), A1 = __shfl(ay, src0);
  int A2 = __shfl(ax, src1), A3 = __shfl(ay, src1);
  int B0 = __shfl(bx, src0), B1 = __shfl(by, src0);
  int B2 = __shfl(bx, src1), B3 = __shfl(by, src1);
  if (g >= 2) { A0 = A1 = A2 = A3 = 0; B0 = B1 = B2 = B3 = 0; }
  s16x8 A8, B8;
  ((int*)&A8)[0] = A0; ((int*)&A8)[1] = A1; ((int*)&A8)[2] = A2; ((int*)&A8)[3] = A3;
  ((int*)&B8)[0] = B0; ((int*)&B8)[1] = B1; ((int*)&B8)[2] = B2; ((int*)&B8)[3] = B3;
  return __builtin_amdgcn_mfma_f32_16x16x32_bf16(A8, B8, c, 0, 0, 0);
#endif
}

// ---- detector: is mask stored as 1-byte bool (flag=1) or int32 (flag=0)? ----
__global__ void detect_mask_kernel(const unsigned char* __restrict__ m, int* __restrict__ flag) {
  int t = threadIdx.x;
  int any = 0;
  for (int u = t; u < 16384; u += 256)
    if ((u & 3) != 0 && m[u] != 0) any = 1;
  unsigned long long bal = __ballot(any != 0);
  if ((t & 63) == 0 && bal != 0ULL) atomicOr(flag, 1);
}

// ---- kernel A: MFMA QKV projection -> bf16. Q scaled by 0.25. V stored transposed. ----
// Qb,Kb: [h][b][n][16] bf16 ; Vt: [h][b][dv][512] bf16
__global__ __launch_bounds__(256) void qkv_proj_mfma(
    const float* __restrict__ q,
    const float* __restrict__ Wq, const float* __restrict__ Wk, const float* __restrict__ Wv,
    short* __restrict__ Qb, short* __restrict__ Kb, short* __restrict__ Vt)
{
  __shared__ short qs[64][136];   // [row][d] bf16, padded
  __shared__ short ws[128][136];  // [col=(h,k)][d] bf16 (W^T), padded

  int blk = blockIdx.x;
  int b = blk >> 3;
  int rt = (blk & 7) * 64;
  int t = threadIdx.x;
  int wid = t >> 6, lane = t & 63;
  int lq = lane & 15, lg = lane >> 4;
  int rowb = wid * 16;

  for (int u = t; u < 64 * 128; u += 256) {
    int r = u >> 7, d = u & 127;
    qs[r][d] = f2bf(q[((size_t)b * Nc + rt + r) * Dc + d]);
  }

  const float* srcs[3] = { Wq, Wk, Wv };
  #pragma unroll 1
  for (int pj = 0; pj < 3; ++pj) {
    __syncthreads();
    const float* W = srcs[pj];
    for (int u = t; u < 16384; u += 256) {
      int h = u >> 11, d = (u >> 4) & 127, k = u & 15;
      ws[h * 16 + k][d] = f2bf(W[u]);
    }
    __syncthreads();

    f32x4 acc[8];
    #pragma unroll
    for (int ct = 0; ct < 8; ++ct) acc[ct] = (f32x4)0.f;

    #pragma unroll 1
    for (int ks = 0; ks < 8; ++ks) {
      s16x4 af = *(const s16x4*)&qs[rowb + lq][ks * 16 + lg * 4];
      #pragma unroll
      for (int ct = 0; ct < 8; ++ct) {
        s16x4 bf = *(const s16x4*)&ws[ct * 16 + lq][ks * 16 + lg * 4];
        acc[ct] = mfma16(af, bf, acc[ct]);
      }
    }

    if (pj == 0) {
      #pragma unroll
      for (int ct = 0; ct < 8; ++ct)
        #pragma unroll
        for (int r = 0; r < 4; ++r)
          Qb[(((size_t)ct * Bc + b) * Nc + rt + rowb + lg * 4 + r) * DKc + lq] = f2bf(acc[ct][r] * 0.25f);
    } else if (pj == 1) {
      #pragma unroll
      for (int ct = 0; ct < 8; ++ct)
        #pragma unroll
        for (int r = 0; r < 4; ++r)
          Kb[(((size_t)ct * Bc + b) * Nc + rt + rowb + lg * 4 + r) * DKc + lq] = f2bf(acc[ct][r]);
    } else {
      #pragma unroll
      for (int ct = 0; ct < 8; ++ct) {
        s16x4 pk = pack4(acc[ct][0], acc[ct][1], acc[ct][2], acc[ct][3]);
        *(s16x4*)&Vt[(((size_t)ct * Bc + b) * DKc + lq) * Nc + rt + rowb + lg * 4] = pk;
      }
    }
  }
}

// ---- kernel B: fused edge-MLP(MFMA) + masked softmax attention, block = (b, 16 q rows) ----
// LDS per wave: bias [16j][9h][17q] fp32 (2448 dw) ; etile [16][16] fp32
__global__ __launch_bounds__(256, 3) void attn_fused2(
    const float* __restrict__ edge, const unsigned char* __restrict__ maskB,
    const int* __restrict__ flag,
    const short* __restrict__ Qb, const short* __restrict__ Kb, const short* __restrict__ Vt,
    const float* __restrict__ Wout,
    const float* __restrict__ mW1, const float* __restrict__ mb1,
    const float* __restrict__ mW2, const float* __restrict__ mb2,
    const float* __restrict__ mW3, const float* __restrict__ mb3,
    float* __restrict__ out)
{
  __shared__ float bias_s[4][2448];   // per-wave [j][h(9)][q(17)]; overlay: [8][16][17] Opartial + sums@2176
  __shared__ float etile[4][16][16];

  int t = threadIdx.x;
  int wid = t >> 6, lane = t & 63;
  int lq = lane & 15, lg = lane >> 4;
  int b = blockIdx.x >> 5;
  int qt = (blockIdx.x & 31) * 16;
  int mflag = *flag;

  // MLP weight fragments (registers)
  float W1v[4], b1v[4], b2v[4], b3v[4];
  s16x4 w2f, w3f;
  #pragma unroll
  for (int i = 0; i < 4; ++i) {
    int v = lg * 4 + i;
    W1v[i] = mW1[v];
    b1v[i] = mb1[v];
    b2v[i] = mb2[v];
    b3v[i] = (v < 8) ? mb3[v] : 0.f;
    w2f[i] = f2bf(mW2[v * 16 + lq]);                  // W2^T[u=lq][v]
    w3f[i] = (lq < 8) ? f2bf(mW3[v * 8 + lq]) : (short)0;  // W3^T[h=lq][v]
  }

  // Q fragments per head: Q^T[d=lg*4+i][q=lq]
  s16x4 qf[8];
  #pragma unroll
  for (int h = 0; h < 8; ++h)
    qf[h] = *(const s16x4*)&Qb[(((size_t)h * Bc + b) * Nc + qt + lq) * DKc + lg * 4];

  f32x4 oacc[8];
  float psum[8];
  #pragma unroll
  for (int h = 0; h < 8; ++h) { oacc[h] = (f32x4)0.f; psum[h] = 0.f; }

  float* bw = &bias_s[wid][0];

  #pragma unroll 1
  for (int cc = 0; cc < 8; ++cc) {
    int jb = ((cc << 2) | wid) << 4;   // this wave's 16-key chunk

    // stage edge tile (wave-private, no barrier needed)
    {
      float4 ev = *(const float4*)&edge[((size_t)b * Nc + qt + (lane >> 2)) * Nc + jb + (lane & 3) * 4];
      *(float4*)&etile[wid][lane >> 2][(lane & 3) * 4] = ev;
    }
    // mask for this lane's S^T slots: (q=lq, j=jb+lg*4+r)
    int mk0, mk1, mk2, mk3;
    {
      size_t mbase = ((size_t)b * Nc + qt + lq) * Nc + jb + lg * 4;
      if (mflag) {
        uchar4 mv = *(const uchar4*)&maskB[mbase];
        mk0 = mv.x; mk1 = mv.y; mk2 = mv.z; mk3 = mv.w;
      } else {
        int4 mv = *(const int4*)&((const int*)maskB)[mbase];
        mk0 = mv.x; mk1 = mv.y; mk2 = mv.z; mk3 = mv.w;
      }
    }

    // edge MLP via MFMA, one q-row at a time; bias -> LDS [j][h][q]
    #pragma unroll 4
    for (int qq = 0; qq < 16; ++qq) {
      float e = etile[wid][qq][lq];
      s16x4 h1f = pack4(fmaxf(0.f, fmaf(e, W1v[0], b1v[0])),
                        fmaxf(0.f, fmaf(e, W1v[1], b1v[1])),
                        fmaxf(0.f, fmaf(e, W1v[2], b1v[2])),
                        fmaxf(0.f, fmaf(e, W1v[3], b1v[3])));
      f32x4 c2; c2[0] = b2v[0]; c2[1] = b2v[1]; c2[2] = b2v[2]; c2[3] = b2v[3];
      c2 = mfma16(w2f, h1f, c2);                 // h2^T[u][j]
      s16x4 rf = pack4(fmaxf(c2[0], 0.f), fmaxf(c2[1], 0.f), fmaxf(c2[2], 0.f), fmaxf(c2[3], 0.f));
      f32x4 c3; c3[0] = b3v[0]; c3[1] = b3v[1]; c3[2] = b3v[2]; c3[3] = b3v[3];
      c3 = mfma16(w3f, rf, c3);                  // bias^T[h][j]
      if (lg < 2) {
        #pragma unroll
        for (int r = 0; r < 4; ++r)
          bw[lq * 153 + (lg * 4 + r) * 17 + qq] = c3[r];   // [j=lq][h][q]
      }
    }

    // per-head: S^T = K.Q^T + bias ; p = exp ; O^T += V^T.P^T
    #pragma unroll
    for (int h = 0; h < 8; ++h) {
      f32x4 sc;
      #pragma unroll
      for (int r = 0; r < 4; ++r)
        sc[r] = bw[(lg * 4 + r) * 153 + h * 17 + lq];      // bias[j=lg*4+r][h][q=lq]
      s16x4 kf = *(const s16x4*)&Kb[(((size_t)h * Bc + b) * Nc + jb + lq) * DKc + lg * 4];
      sc = mfma16(kf, qf[h], sc);
      float p0 = mk0 ? 0.f : __expf(sc[0]);
      float p1 = mk1 ? 0.f : __expf(sc[1]);
      float p2 = mk2 ? 0.f : __expf(sc[2]);
      float p3 = mk3 ? 0.f : __expf(sc[3]);
      psum[h] += (p0 + p1) + (p2 + p3);
      s16x4 pf = pack4(p0, p1, p2, p3);
      s16x4 vf = *(const s16x4*)&Vt[(((size_t)h * Bc + b) * DKc + lq) * Nc + jb + lg * 4];
      oacc[h] = mfma16(vf, pf, oacc[h]);
    }
  }

  // ---- epilogue: per-wave partials -> LDS (overlay bias region), combine, normalize ----
  __syncthreads();   // everyone done with bias reads
  #pragma unroll
  for (int h = 0; h < 8; ++h) {
    #pragma unroll
    for (int r = 0; r < 4; ++r)
      bw[(h * 16 + lg * 4 + r) * 17 + lq] = oacc[h][r];    // O^T[h][dv][q]
    float s = psum[h];
    s += __shfl_xor(s, 16);
    s += __shfl_xor(s, 32);
    if (lane < 16) bw[2176 + h * 16 + lq] = s;
  }
  __syncthreads();

  // combine 4 wave-partials + divide by sum; result in bias_s[0] region
  for (int u = t; u < 2048; u += 256) {
    int hh = u >> 8, dv = (u >> 4) & 15, qq = u & 15;
    int off = (hh * 16 + dv) * 17 + qq;
    float a = bias_s[0][off] + bias_s[1][off] + bias_s[2][off] + bias_s[3][off];
    float sm = bias_s[0][2176 + hh * 16 + qq] + bias_s[1][2176 + hh * 16 + qq]
             + bias_s[2][2176 + hh * 16 + qq] + bias_s[3][2176 + hh * 16 + qq];
    bias_s[0][off] = (sm != 0.f) ? a / sm : 0.f;
  }
  __syncthreads();

  // output projection: out[b][qt+q][e] = sum_hd O_n[hd][q] * Wout[hd][e]
  {
    int e = t & 127, qh = t >> 7;
    float acc[8];
    #pragma unroll
    for (int i = 0; i < 8; ++i) acc[i] = 0.f;
    #pragma unroll 4
    for (int hd = 0; hd < 128; ++hd) {
      float wv = Wout[hd * Ec + e];
      const float* on = &bias_s[0][hd * 17 + qh * 8];
      #pragma unroll
      for (int i = 0; i < 8; ++i) acc[i] = fmaf(on[i], wv, acc[i]);
    }
    #pragma unroll
    for (int i = 0; i < 8; ++i)
      out[((size_t)b * Nc + qt + qh * 8 + i) * Ec + e] = acc[i];
  }
}

extern "C" void kernel_launch(void* const* d_in, const int* in_sizes, int n_in,
                              void* d_out, int out_size, void* d_ws, size_t ws_size,
                              hipStream_t stream)
{
  const float* q    = (const float*)d_in[0];
  const unsigned char* mask = (const unsigned char*)d_in[1];
  const float* edge = (const float*)d_in[2];
  const float* Wq   = (const float*)d_in[3];
  const float* Wk   = (const float*)d_in[4];
  const float* Wv   = (const float*)d_in[5];
  const float* Wo   = (const float*)d_in[6];
  const float* mW1  = (const float*)d_in[7];
  const float* mb1  = (const float*)d_in[8];
  const float* mW2  = (const float*)d_in[9];
  const float* mb2  = (const float*)d_in[10];
  const float* mW3  = (const float*)d_in[11];
  const float* mb3  = (const float*)d_in[12];
  float* out = (float*)d_out;

  size_t per = (size_t)Hc * Bc * Nc * DKc;     // 2,097,152 bf16 elements per matrix
  short* Qb = (short*)d_ws;
  short* Kb = Qb + per;
  short* Vt = Kb + per;
  int* flag = (int*)(Vt + per);                // ~12.6 MB used

  hipMemsetAsync(flag, 0, sizeof(int), stream);
  detect_mask_kernel<<<1, 256, 0, stream>>>(mask, flag);
  qkv_proj_mfma<<<dim3(Bc * 8), dim3(256), 0, stream>>>(q, Wq, Wk, Wv, Qb, Kb, Vt);
  attn_fused2<<<dim3(Bc * 32), dim3(256), 0, stream>>>(edge, mask, flag, Qb, Kb, Vt, Wo,
      mW1, mb1, mW2, mb2, mW3, mb3, out);
}

// Round 3
// 132.283 us; speedup vs baseline: 4.2300x; 1.1811x over previous
//
#include <hip/hip_runtime.h>
#include <hip/hip_bf16.h>
#include <float.h>

#define Bc 32
#define Nc 512
#define Dc 128
#define Hc 8
#define DKc 16
#define Ec 128
#define LOG2E 1.44269504088896340736f

typedef __attribute__((ext_vector_type(4))) short s16x4;
typedef __attribute__((ext_vector_type(8))) short s16x8;
typedef __attribute__((ext_vector_type(4))) float f32x4;

union BFU { __hip_bfloat16 b; short s; };
static __device__ inline short f2bf(float f) { BFU u; u.b = __float2bfloat16(f); return u.s; }
static __device__ inline s16x4 pack4(float a, float b, float c, float d) {
  s16x4 r; r[0] = f2bf(a); r[1] = f2bf(b); r[2] = f2bf(c); r[3] = f2bf(d); return r;
}

#if __has_builtin(__builtin_amdgcn_exp2f)
#define EXP2F(x) __builtin_amdgcn_exp2f(x)
#else
#define EXP2F(x) exp2f(x)
#endif

// D = A*B + C for 16x16x16 bf16. A[m=l&15][k=(l>>4)*4+i]; B[k][n=l&15];
// C/D: col(n)=l&15, row(m)=(l>>4)*4+reg.
static __device__ inline f32x4 mfma16(s16x4 a, s16x4 b, f32x4 c) {
#if __has_builtin(__builtin_amdgcn_mfma_f32_16x16x16bf16_1k)
  return __builtin_amdgcn_mfma_f32_16x16x16bf16_1k(a, b, c, 0, 0, 0);
#else
  int lane = threadIdx.x & 63;
  int g = lane >> 4, base = lane & 15;
  int src0 = (base + 32 * g) & 63;
  int src1 = (base + 32 * g + 16) & 63;
  int ax = ((int*)&a)[0], ay = ((int*)&a)[1];
  int bx = ((int*)&b)[0], by = ((int*)&b)[1];
  int A0 = __shfl(ax, src0), A1 = __shfl(ay, src0);
  int A2 = __shfl(ax, src1), A3 = __shfl(ay, src1);
  int B0 = __shfl(bx, src0), B1 = __shfl(by, src0);
  int B2 = __shfl(bx, src1), B3 = __shfl(by, src1);
  if (g >= 2) { A0 = A1 = A2 = A3 = 0; B0 = B1 = B2 = B3 = 0; }
  s16x8 A8, B8;
  ((int*)&A8)[0] = A0; ((int*)&A8)[1] = A1; ((int*)&A8)[2] = A2; ((int*)&A8)[3] = A3;
  ((int*)&B8)[0] = B0; ((int*)&B8)[1] = B1; ((int*)&B8)[2] = B2; ((int*)&B8)[3] = B3;
  return __builtin_amdgcn_mfma_f32_16x16x32_bf16(A8, B8, c, 0, 0, 0);
#endif
}

// ---- detector: is mask stored as 1-byte bool (flag=1) or int32 (flag=0)? ----
__global__ void detect_mask_kernel(const unsigned char* __restrict__ m, int* __restrict__ flag) {
  int t = threadIdx.x;
  int any = 0;
  for (int u = t; u < 16384; u += 256)
    if ((u & 3) != 0 && m[u] != 0) any = 1;
  unsigned long long bal = __ballot(any != 0);
  if ((t & 63) == 0 && bal != 0ULL) atomicOr(flag, 1);
}

// ---- convert Wq/Wk/Wv fp32[h][d][k] -> bf16 transposed Wt[mat][h*16+k][d] ----
__global__ __launch_bounds__(256) void convert_w(
    const float* __restrict__ Wq, const float* __restrict__ Wk, const float* __restrict__ Wv,
    short* __restrict__ Wt)
{
  int o = blockIdx.x * 256 + threadIdx.x;   // grid 192 -> 49152
  int mat = o >> 14, r = o & 16383;
  int hk = r >> 7, d = r & 127;
  const float* src = (mat == 0) ? Wq : ((mat == 1) ? Wk : Wv);
  Wt[o] = f2bf(src[(hk >> 4) * 2048 + d * 16 + (hk & 15)]);
}

// ---- kernel A: QKV projection via MFMA, weights from global bf16 (L2-hot). ----
// Qb (scaled 0.25*log2e), Kb: [h][b][n][16] bf16 ; Vt: [h][b][dv][512] bf16
__global__ __launch_bounds__(256) void qkv_proj3(
    const float* __restrict__ q, const short* __restrict__ Wt,
    short* __restrict__ Qb, short* __restrict__ Kb, short* __restrict__ Vt)
{
  __shared__ short qs[64][136];
  int blk = blockIdx.x;
  int b = blk >> 3;
  int rt = (blk & 7) * 64;
  int t = threadIdx.x;
  int wid = t >> 6, lane = t & 63;
  int lq = lane & 15, lg = lane >> 4;
  int rowb = wid * 16;

  for (int u = t; u < 2048; u += 256) {
    int row = u >> 5, c4 = (u & 31) * 4;
    float4 v = *(const float4*)&q[(((b << 9) + rt + row) << 7) + c4];
    s16x4 pk = pack4(v.x, v.y, v.z, v.w);
    *(s16x4*)&qs[row][c4] = pk;
  }
  __syncthreads();

  #pragma unroll 1
  for (int pj = 0; pj < 3; ++pj) {
    const short* Wm = Wt + pj * 16384;
    f32x4 acc[8];
    #pragma unroll
    for (int ct = 0; ct < 8; ++ct) acc[ct] = (f32x4)0.f;

    #pragma unroll 1
    for (int ks = 0; ks < 8; ++ks) {
      s16x4 af = *(const s16x4*)&qs[rowb + lq][ks * 16 + lg * 4];
      #pragma unroll
      for (int ct = 0; ct < 8; ++ct) {
        s16x4 bf = *(const s16x4*)&Wm[(ct * 16 + lq) * 128 + ks * 16 + lg * 4];
        acc[ct] = mfma16(af, bf, acc[ct]);
      }
    }

    if (pj == 0) {
      #pragma unroll
      for (int ct = 0; ct < 8; ++ct)
        #pragma unroll
        for (int r = 0; r < 4; ++r)
          Qb[(ct << 18) + (b << 13) + ((rt + rowb + lg * 4 + r) << 4) + lq] =
              f2bf(acc[ct][r] * (0.25f * LOG2E));
    } else if (pj == 1) {
      #pragma unroll
      for (int ct = 0; ct < 8; ++ct)
        #pragma unroll
        for (int r = 0; r < 4; ++r)
          Kb[(ct << 18) + (b << 13) + ((rt + rowb + lg * 4 + r) << 4) + lq] = f2bf(acc[ct][r]);
    } else {
      #pragma unroll
      for (int ct = 0; ct < 8; ++ct) {
        s16x4 pk = pack4(acc[ct][0], acc[ct][1], acc[ct][2], acc[ct][3]);
        *(s16x4*)&Vt[(ct << 18) + (((b << 4) + lq) << 9) + rt + rowb + lg * 4] = pk;
      }
    }
  }
}

// ---- kernel B: fused edge-MLP(MFMA) + masked softmax attention ----
// block = (b, 16 q rows); per-wave bias region 2176 dw: MLP bias [j16]*130+[h8]*16+[q16];
// epilogue overlay: Opart[hd128][q16] + sums[128] @2048.
__global__ __launch_bounds__(256, 4) void attn_fused3(
    const float* __restrict__ edge, const unsigned char* __restrict__ maskB,
    const int* __restrict__ flag,
    const short* __restrict__ Qb, const short* __restrict__ Kb, const short* __restrict__ Vt,
    const float* __restrict__ Wout,
    const float* __restrict__ mW1, const float* __restrict__ mb1,
    const float* __restrict__ mW2, const float* __restrict__ mb2,
    const float* __restrict__ mW3, const float* __restrict__ mb3,
    float* __restrict__ out)
{
  __shared__ float bias_s[4][2176];
  __shared__ float etile[4][16][16];

  int t = threadIdx.x;
  int wid = t >> 6, lane = t & 63;
  int lq = lane & 15, lg = lane >> 4;
  int b = blockIdx.x >> 5;
  int qt = (blockIdx.x & 31) * 16;
  int mflag = *flag;

  // MLP weight fragments (W3/b3 pre-scaled by log2e for exp2)
  float W1v[4], b1v[4];
  f32x4 b2v, b3v;
  s16x4 w2f, w3f;
  #pragma unroll
  for (int i = 0; i < 4; ++i) {
    int v = lg * 4 + i;
    W1v[i] = mW1[v];
    b1v[i] = mb1[v];
    b2v[i] = mb2[v];
    b3v[i] = (v < 8) ? mb3[v] * LOG2E : 0.f;
    w2f[i] = f2bf(mW2[v * 16 + lq]);
    w3f[i] = (lq < 8) ? f2bf(mW3[v * 8 + lq] * LOG2E) : (short)0;
  }

  // lane-hoisted bases (32-bit offsets)
  const short* Kl = Kb + (b << 13) + (lq << 4) + (lg << 2);
  const short* Vl = Vt + (((b << 4) + lq) << 9) + (lg << 2);
  const short* Ql = Qb + (b << 13) + ((qt + lq) << 4) + (lg << 2);
  unsigned ebase = (((b << 9) + qt + (lane >> 2)) << 9) + (lane & 3) * 4;
  unsigned mbase = (((b << 9) + qt + lq) << 9) + (lg << 2);

  s16x4 qf[8];
  #pragma unroll
  for (int h = 0; h < 8; ++h) qf[h] = *(const s16x4*)(Ql + (h << 18));

  f32x4 oacc[8];
  float psum[8];
  #pragma unroll
  for (int h = 0; h < 8; ++h) { oacc[h] = (f32x4)0.f; psum[h] = 0.f; }

  float* bw = &bias_s[wid][0];

  // pipeline prologue: chunk 0 edge+mask
  int jb = wid << 4;
  float4 ev = *(const float4*)&edge[ebase + jb];
  int4 mkv;
  if (mflag) {
    uchar4 u = *(const uchar4*)&maskB[mbase + jb];
    mkv.x = u.x; mkv.y = u.y; mkv.z = u.z; mkv.w = u.w;
  } else {
    mkv = *(const int4*)&((const int*)maskB)[mbase + jb];
  }

  #pragma unroll 1
  for (int cc = 0; cc < 8; ++cc) {
    jb = ((cc << 2) | wid) << 4;
    *(float4*)&etile[wid][lane >> 2][(lane & 3) * 4] = ev;

    // prefetch next chunk's edge + mask
    float4 evn; int4 mkn;
    if (cc < 7) {
      int jbn = (((cc + 1) << 2) | wid) << 4;
      evn = *(const float4*)&edge[ebase + jbn];
      if (mflag) {
        uchar4 u = *(const uchar4*)&maskB[mbase + jbn];
        mkn.x = u.x; mkn.y = u.y; mkn.z = u.z; mkn.w = u.w;
      } else {
        mkn = *(const int4*)&((const int*)maskB)[mbase + jbn];
      }
    } else { evn = ev; mkn = mkv; }

    // prefetch K fragments for all heads (consumed after the MLP phase)
    s16x4 kf[8];
    #pragma unroll
    for (int h = 0; h < 8; ++h) kf[h] = *(const s16x4*)(Kl + (h << 18) + (jb << 4));

    // edge MLP via MFMA, one q-row at a time; bias -> LDS [j]*130+[h]*16+[q]
    #pragma unroll 4
    for (int qq = 0; qq < 16; ++qq) {
      float e = etile[wid][qq][lq];
      s16x4 h1f = pack4(fmaxf(0.f, fmaf(e, W1v[0], b1v[0])),
                        fmaxf(0.f, fmaf(e, W1v[1], b1v[1])),
                        fmaxf(0.f, fmaf(e, W1v[2], b1v[2])),
                        fmaxf(0.f, fmaf(e, W1v[3], b1v[3])));
      f32x4 c2 = mfma16(w2f, h1f, b2v);          // h2^T[u][j]
      s16x4 rf = pack4(fmaxf(c2[0], 0.f), fmaxf(c2[1], 0.f),
                       fmaxf(c2[2], 0.f), fmaxf(c2[3], 0.f));
      f32x4 c3 = mfma16(w3f, rf, b3v);           // (log2e*bias)^T[h][j]
      if (lg < 2) {
        #pragma unroll
        for (int r = 0; r < 4; ++r)
          bw[lq * 130 + (lg * 4 + r) * 16 + qq] = c3[r];
      }
    }

    // per-head: S^T = K.Q^T + bias' ; p = exp2 ; O^T += V^T.P^T
    #pragma unroll
    for (int h = 0; h < 8; ++h) {
      f32x4 sc;
      #pragma unroll
      for (int r = 0; r < 4; ++r)
        sc[r] = bw[(lg * 4 + r) * 130 + h * 16 + lq];
      sc = mfma16(kf[h], qf[h], sc);
      s16x4 vf = *(const s16x4*)(Vl + (h << 18) + jb);
      float p0 = mkv.x ? 0.f : EXP2F(sc[0]);
      float p1 = mkv.y ? 0.f : EXP2F(sc[1]);
      float p2 = mkv.z ? 0.f : EXP2F(sc[2]);
      float p3 = mkv.w ? 0.f : EXP2F(sc[3]);
      psum[h] += (p0 + p1) + (p2 + p3);
      s16x4 pf = pack4(p0, p1, p2, p3);
      oacc[h] = mfma16(vf, pf, oacc[h]);
    }
    ev = evn; mkv = mkn;
  }

  // ---- epilogue ----
  __syncthreads();
  #pragma unroll
  for (int h = 0; h < 8; ++h) {
    #pragma unroll
    for (int r = 0; r < 4; ++r)
      bw[(h * 16 + lg * 4 + r) * 16 + lq] = oacc[h][r];    // Opart[hd][q]
    float s = psum[h];
    s += __shfl_xor(s, 16);
    s += __shfl_xor(s, 32);
    if (lane < 16) bw[2048 + h * 16 + lq] = s;
  }
  __syncthreads();

  // combine 4 wave-partials + normalize (in-place into bias_s[0])
  for (int u = t; u < 2048; u += 256) {
    float a = bias_s[0][u] + bias_s[1][u] + bias_s[2][u] + bias_s[3][u];
    int si = 2048 + ((u >> 8) << 4) + (u & 15);
    float sm = bias_s[0][si] + bias_s[1][si] + bias_s[2][si] + bias_s[3][si];
    bias_s[0][u] = (sm != 0.f) ? a / sm : 0.f;
  }
  __syncthreads();

  // output projection: out[b][qt+q][e] = sum_hd On[hd][q] * Wout[hd][e]
  {
    int e = t & 127, qh = t >> 7;
    float acc[8];
    #pragma unroll
    for (int i = 0; i < 8; ++i) acc[i] = 0.f;
    #pragma unroll 4
    for (int hd = 0; hd < 128; ++hd) {
      float wv = Wout[hd * Ec + e];
      const float* on = &bias_s[0][hd * 16 + qh * 8];
      #pragma unroll
      for (int i = 0; i < 8; ++i) acc[i] = fmaf(on[i], wv, acc[i]);
    }
    #pragma unroll
    for (int i = 0; i < 8; ++i)
      out[(((b << 9) + qt + qh * 8 + i) << 7) + e] = acc[i];
  }
}

extern "C" void kernel_launch(void* const* d_in, const int* in_sizes, int n_in,
                              void* d_out, int out_size, void* d_ws, size_t ws_size,
                              hipStream_t stream)
{
  const float* q    = (const float*)d_in[0];
  const unsigned char* mask = (const unsigned char*)d_in[1];
  const float* edge = (const float*)d_in[2];
  const float* Wq   = (const float*)d_in[3];
  const float* Wk   = (const float*)d_in[4];
  const float* Wv   = (const float*)d_in[5];
  const float* Wo   = (const float*)d_in[6];
  const float* mW1  = (const float*)d_in[7];
  const float* mb1  = (const float*)d_in[8];
  const float* mW2  = (const float*)d_in[9];
  const float* mb2  = (const float*)d_in[10];
  const float* mW3  = (const float*)d_in[11];
  const float* mb3  = (const float*)d_in[12];
  float* out = (float*)d_out;

  size_t per = (size_t)Hc * Bc * Nc * DKc;     // 2,097,152 bf16 elems per matrix
  short* Wt = (short*)d_ws;                    // 49152 bf16
  short* Qb = Wt + 49152;
  short* Kb = Qb + per;
  short* Vt = Kb + per;
  int* flag = (int*)(Vt + per);                // ~12.7 MB used

  hipMemsetAsync(flag, 0, sizeof(int), stream);
  detect_mask_kernel<<<1, 256, 0, stream>>>(mask, flag);
  convert_w<<<dim3(192), dim3(256), 0, stream>>>(Wq, Wk, Wv, Wt);
  qkv_proj3<<<dim3(Bc * 8), dim3(256), 0, stream>>>(q, Wt, Qb, Kb, Vt);
  attn_fused3<<<dim3(Bc * 32), dim3(256), 0, stream>>>(edge, mask, flag, Qb, Kb, Vt, Wo,
      mW1, mb1, mW2, mb2, mW3, mb3, out);
}

// Round 5
// 130.042 us; speedup vs baseline: 4.3029x; 1.0172x over previous
//
#include <hip/hip_runtime.h>
#include <hip/hip_bf16.h>
#include <float.h>

#define Bc 32
#define Nc 512
#define Dc 128
#define Hc 8
#define DKc 16
#define Ec 128
#define LOG2E 1.44269504088896340736f
#define SCLAMP 80.0f

typedef __attribute__((ext_vector_type(4))) short s16x4;
typedef __attribute__((ext_vector_type(8))) short s16x8;
typedef __attribute__((ext_vector_type(4))) float f32x4;

union BFU { __hip_bfloat16 b; short s; };
static __device__ inline short f2bf(float f) { BFU u; u.b = __float2bfloat16(f); return u.s; }
static __device__ inline s16x4 pack4(float a, float b, float c, float d) {
  s16x4 r; r[0] = f2bf(a); r[1] = f2bf(b); r[2] = f2bf(c); r[3] = f2bf(d); return r;
}

#if __has_builtin(__builtin_amdgcn_exp2f)
#define EXP2F(x) __builtin_amdgcn_exp2f(x)
#else
#define EXP2F(x) exp2f(x)
#endif

// D = A*B + C for 16x16x16 bf16. A[m=l&15][k=(l>>4)*4+i]; B[k=(l>>4)*4+i][n=l&15];
// C/D: col(n)=l&15, row(m)=(l>>4)*4+reg.
static __device__ inline f32x4 mfma16(s16x4 a, s16x4 b, f32x4 c) {
#if __has_builtin(__builtin_amdgcn_mfma_f32_16x16x16bf16_1k)
  return __builtin_amdgcn_mfma_f32_16x16x16bf16_1k(a, b, c, 0, 0, 0);
#else
  int lane = threadIdx.x & 63;
  int g = lane >> 4, base = lane & 15;
  int src0 = (base + 32 * g) & 63;
  int src1 = (base + 32 * g + 16) & 63;
  int ax = ((int*)&a)[0], ay = ((int*)&a)[1];
  int bx = ((int*)&b)[0], by = ((int*)&b)[1];
  int A0 = __shfl(ax, src0), A1 = __shfl(ay, src0);
  int A2 = __shfl(ax, src1), A3 = __shfl(ay, src1);
  int B0 = __shfl(bx, src0), B1 = __shfl(by, src0);
  int B2 = __shfl(bx, src1), B3 = __shfl(by, src1);
  if (g >= 2) { A0 = A1 = A2 = A3 = 0; B0 = B1 = B2 = B3 = 0; }
  s16x8 A8, B8;
  ((int*)&A8)[0] = A0; ((int*)&A8)[1] = A1; ((int*)&A8)[2] = A2; ((int*)&A8)[3] = A3;
  ((int*)&B8)[0] = B0; ((int*)&B8)[1] = B1; ((int*)&B8)[2] = B2; ((int*)&B8)[3] = B3;
  return __builtin_amdgcn_mfma_f32_16x16x32_bf16(A8, B8, c, 0, 0, 0);
#endif
}

// ---- merged: mask-format detector (block 256) + weight converter (blocks 0..255) ----
// Wt[mat][h*16+k][d] bf16 (49152) ; Wob[et][s][lane][i] bf16 (16384)
__global__ __launch_bounds__(256) void conv_detect(
    const float* __restrict__ Wq, const float* __restrict__ Wk, const float* __restrict__ Wv,
    const float* __restrict__ Wo,
    const unsigned char* __restrict__ m, int* __restrict__ flag,
    short* __restrict__ Wt, short* __restrict__ Wob)
{
  int blk = blockIdx.x;
  int t = threadIdx.x;
  if (blk == 256) {   // detector
    int any = 0;
    for (int u = t; u < 16384; u += 256)
      if ((u & 3) != 0 && m[u] != 0) any = 1;
    unsigned long long bal = __ballot(any != 0);
    if ((t & 63) == 0 && bal != 0ULL) atomicOr(flag, 1);
    return;
  }
  int o = blk * 256 + t;
  if (o < 49152) {
    int mat = o >> 14, r = o & 16383;
    int hk = r >> 7, d = r & 127;
    const float* src = (mat == 0) ? Wq : ((mat == 1) ? Wk : Wv);
    Wt[o] = f2bf(src[(hk >> 4) * 2048 + d * 16 + (hk & 15)]);
  } else {
    int o2 = o - 49152;
    int et = o2 >> 11, s = (o2 >> 8) & 7, lane = (o2 >> 2) & 63, i = o2 & 3;
    Wob[o2] = f2bf(Wo[(s * 16 + (lane >> 4) * 4 + i) * 128 + et * 16 + (lane & 15)]);
  }
}

// ---- kernel A: QKV projection via MFMA; 16-row tiles, waves split output col-tiles ----
// Qb (scaled 0.25*log2e), Kb: [h][b][n][16] bf16 ; Vt: [h][b][dv][512] bf16
__global__ __launch_bounds__(256, 4) void qkv4(
    const float* __restrict__ q, const short* __restrict__ Wt,
    short* __restrict__ Qb, short* __restrict__ Kb, short* __restrict__ Vt)
{
  __shared__ short qs[16][136];
  int blk = blockIdx.x;
  int b = blk >> 5;
  int rt = (blk & 31) << 4;
  int t = threadIdx.x;
  int wid = t >> 6, lane = t & 63;
  int lq = lane & 15, lg = lane >> 4;

  #pragma unroll
  for (int it = 0; it < 2; ++it) {
    int u = t + it * 256;
    int row = u >> 5, c4 = (u & 31) << 2;
    float4 v = *(const float4*)&q[((((b << 9) + rt + row) << 7)) + c4];
    *(s16x4*)&qs[row][c4] = pack4(v.x, v.y, v.z, v.w);
  }
  __syncthreads();

  s16x4 af[8];
  #pragma unroll
  for (int ks = 0; ks < 8; ++ks)
    af[ks] = *(const s16x4*)&qs[lq][ks * 16 + lg * 4];

  #pragma unroll 1
  for (int pj = 0; pj < 3; ++pj) {
    const short* Wm = Wt + pj * 16384;
    #pragma unroll
    for (int c2 = 0; c2 < 2; ++c2) {
      int ct = wid * 2 + c2;
      f32x4 acc = (f32x4)0.f;
      #pragma unroll
      for (int ks = 0; ks < 8; ++ks) {
        s16x4 bf = *(const s16x4*)&Wm[(ct * 16 + lq) * 128 + ks * 16 + lg * 4];
        acc = mfma16(af[ks], bf, acc);
      }
      if (pj == 0) {
        s16x4 pk = pack4(acc[0] * (0.25f * LOG2E), acc[1] * (0.25f * LOG2E),
                         acc[2] * (0.25f * LOG2E), acc[3] * (0.25f * LOG2E));
        #pragma unroll
        for (int r = 0; r < 4; ++r)
          Qb[(ct << 18) + (b << 13) + ((rt + lg * 4 + r) << 4) + lq] = pk[r];
      } else if (pj == 1) {
        s16x4 pk = pack4(acc[0], acc[1], acc[2], acc[3]);
        #pragma unroll
        for (int r = 0; r < 4; ++r)
          Kb[(ct << 18) + (b << 13) + ((rt + lg * 4 + r) << 4) + lq] = pk[r];
      } else {
        s16x4 pk = pack4(acc[0], acc[1], acc[2], acc[3]);
        *(s16x4*)&Vt[(ct << 18) + (((b << 4) + lq) << 9) + rt + lg * 4] = pk;
      }
    }
  }
}

// ---- kernel B: fused edge-MLP + masked softmax attention + MFMA out-projection ----
// Block = (b, 16 q-rows); 4 waves each own 8 of the 32 key-chunks (no main-loop barriers).
// LDS: per-wave bf16 bias [8h][16q][20j] (5120B) + etile [16][16] f32 (1024B);
//      epilogue overlay: d2 partials [4][128][17] f32 (34816B) + psum [4][8][16] f32 (2048B).
__global__ __launch_bounds__(256, 4) void attn5(
    const float* __restrict__ edge, const unsigned char* __restrict__ maskB,
    const int* __restrict__ flag,
    const short* __restrict__ Qb, const short* __restrict__ Kb, const short* __restrict__ Vt,
    const short* __restrict__ Wob,
    const float* __restrict__ mW1, const float* __restrict__ mb1,
    const float* __restrict__ mW2, const float* __restrict__ mb2,
    const float* __restrict__ mW3, const float* __restrict__ mb3,
    float* __restrict__ out)
{
  __shared__ __align__(16) char smem[36864];

  int t = threadIdx.x;
  int wid = t >> 6, lane = t & 63;
  int lq = lane & 15, lg = lane >> 4;
  int b = blockIdx.x >> 5;
  int qt = (blockIdx.x & 31) << 4;
  int mflag = *flag;

  short* bias_w = (short*)(smem + wid * 5120);             // [h][q][20]
  float (*etile)[16] = (float(*)[16])(smem + 20480 + wid * 1024);
  float* d2L = (float*)smem;                                // [4][128][17]
  float* psL = (float*)(smem + 34816);                      // [4][8][16]

  // MLP weight fragments (W3/b3 pre-scaled by log2e)
  float W1v[4], b1v[4];
  f32x4 b2v, b3v;
  s16x4 w2f, w3f;
  #pragma unroll
  for (int i = 0; i < 4; ++i) {
    int v = lg * 4 + i;
    W1v[i] = mW1[v];
    b1v[i] = mb1[v];
    b2v[i] = mb2[v];
    b3v[i] = (v < 8) ? mb3[v] * LOG2E : 0.f;
    w2f[i] = f2bf(mW2[v * 16 + lq]);
    w3f[i] = (lq < 8) ? f2bf(mW3[v * 8 + lq] * LOG2E) : (short)0;
  }

  const short* Kl = Kb + (b << 13) + (lq << 4) + (lg << 2);
  const short* Vl = Vt + (((b << 4) + lq) << 9) + (lg << 2);
  const short* Ql = Qb + (b << 13) + ((qt + lq) << 4) + (lg << 2);
  unsigned ebase = (((b << 9) + qt + (lane >> 2)) << 9) + (lane & 3) * 4;
  unsigned mbase = (((b << 9) + qt + lq) << 9) + (lg << 2);

  s16x4 qf[8];
  #pragma unroll
  for (int h = 0; h < 8; ++h) qf[h] = *(const s16x4*)(Ql + (h << 18));

  f32x4 oacc[8];
  float psum[8];
  #pragma unroll
  for (int h = 0; h < 8; ++h) { oacc[h] = (f32x4)0.f; psum[h] = 0.f; }

  // prologue: this wave's chunk 0
  int jb = wid << 4;
  float4 ev = *(const float4*)&edge[ebase + jb];
  int4 mkv;
  if (mflag) {
    uchar4 u = *(const uchar4*)&maskB[mbase + jb];
    mkv.x = u.x; mkv.y = u.y; mkv.z = u.z; mkv.w = u.w;
  } else {
    mkv = *(const int4*)&((const int*)maskB)[mbase + jb];
  }

  #pragma unroll 1
  for (int cc = 0; cc < 8; ++cc) {
    jb = ((cc << 2) | wid) << 4;
    *(float4*)&etile[lane >> 2][(lane & 3) * 4] = ev;

    float4 evn; int4 mkn;
    if (cc < 7) {
      int jbn = (((cc + 1) << 2) | wid) << 4;
      evn = *(const float4*)&edge[ebase + jbn];
      if (mflag) {
        uchar4 u = *(const uchar4*)&maskB[mbase + jbn];
        mkn.x = u.x; mkn.y = u.y; mkn.z = u.z; mkn.w = u.w;
      } else {
        mkn = *(const int4*)&((const int*)maskB)[mbase + jbn];
      }
    } else { evn = ev; mkn = mkv; }

    s16x4 kf[8];
    #pragma unroll
    for (int h = 0; h < 8; ++h) kf[h] = *(const s16x4*)(Kl + (h << 18) + (jb << 4));

    // edge MLP; bias (log2e-scaled) -> bf16 LDS [h][q][j]
    #pragma unroll 4
    for (int qq = 0; qq < 16; ++qq) {
      float e = etile[qq][lq];
      s16x4 h1f = pack4(fmaxf(0.f, fmaf(e, W1v[0], b1v[0])),
                        fmaxf(0.f, fmaf(e, W1v[1], b1v[1])),
                        fmaxf(0.f, fmaf(e, W1v[2], b1v[2])),
                        fmaxf(0.f, fmaf(e, W1v[3], b1v[3])));
      f32x4 c2 = mfma16(w2f, h1f, b2v);
      s16x4 rf = pack4(fmaxf(c2[0], 0.f), fmaxf(c2[1], 0.f),
                       fmaxf(c2[2], 0.f), fmaxf(c2[3], 0.f));
      f32x4 c3 = mfma16(w3f, rf, b3v);
      if (lg < 2) {
        s16x4 pk = pack4(c3[0], c3[1], c3[2], c3[3]);
        #pragma unroll
        for (int r = 0; r < 4; ++r)
          bias_w[(lg * 4 + r) * 320 + qq * 20 + lq] = pk[r];
      }
    }

    // per-head: S^T = K.Q^T + bias' ; p = exp2(min(sc,80)) ; O^T += V^T.P^T
    #pragma unroll
    for (int h = 0; h < 8; ++h) {
      union { s16x4 v; int i[2]; } bb;
      bb.v = *(const s16x4*)&bias_w[h * 320 + lq * 20 + lg * 4];
      f32x4 sc;
      sc[0] = __int_as_float(bb.i[0] << 16);
      sc[1] = __int_as_float(bb.i[0] & 0xffff0000);
      sc[2] = __int_as_float(bb.i[1] << 16);
      sc[3] = __int_as_float(bb.i[1] & 0xffff0000);
      sc = mfma16(kf[h], qf[h], sc);
      s16x4 vf = *(const s16x4*)(Vl + (h << 18) + jb);
      float p0 = mkv.x ? 0.f : EXP2F(fminf(sc[0], SCLAMP));
      float p1 = mkv.y ? 0.f : EXP2F(fminf(sc[1], SCLAMP));
      float p2 = mkv.z ? 0.f : EXP2F(fminf(sc[2], SCLAMP));
      float p3 = mkv.w ? 0.f : EXP2F(fminf(sc[3], SCLAMP));
      psum[h] += (p0 + p1) + (p2 + p3);
      s16x4 pf = pack4(p0, p1, p2, p3);
      oacc[h] = mfma16(vf, pf, oacc[h]);
    }
    ev = evn; mkv = mkn;
  }

  // ---- epilogue: cross-wave psum, normalize, MFMA out-projection, merge ----
  #pragma unroll
  for (int h = 0; h < 8; ++h) {
    float s = psum[h];
    s += __shfl_xor(s, 16);
    s += __shfl_xor(s, 32);
    psum[h] = s;
  }
  if (lg == 0) {
    #pragma unroll
    for (int h = 0; h < 8; ++h) psL[wid * 128 + h * 16 + lq] = psum[h];
  }
  __syncthreads();

  s16x4 obf[8];
  #pragma unroll
  for (int h = 0; h < 8; ++h) {
    float tot = psL[h * 16 + lq] + psL[128 + h * 16 + lq]
              + psL[256 + h * 16 + lq] + psL[384 + h * 16 + lq];
    float inv = (tot > 0.f) ? 1.f / tot : 0.f;
    obf[h] = pack4(oacc[h][0] * inv, oacc[h][1] * inv, oacc[h][2] * inv, oacc[h][3] * inv);
  }

  f32x4 d2a[8];
  #pragma unroll
  for (int et = 0; et < 8; ++et) d2a[et] = (f32x4)0.f;
  #pragma unroll
  for (int s = 0; s < 8; ++s) {
    #pragma unroll
    for (int et = 0; et < 8; ++et) {
      s16x4 wo = *(const s16x4*)&Wob[((et * 8 + s) << 8) + (lane << 2)];
      d2a[et] = mfma16(wo, obf[s], d2a[et]);
    }
  }

  // write partials (overlay region; all waves past their bias reads via barrier above)
  #pragma unroll
  for (int et = 0; et < 8; ++et)
    #pragma unroll
    for (int r = 0; r < 4; ++r)
      d2L[(wid * 128 + et * 16 + lg * 4 + r) * 17 + lq] = d2a[et][r];
  __syncthreads();

  // merge: wave w handles e-tiles {2w, 2w+1}
  #pragma unroll
  for (int k = 0; k < 2; ++k) {
    int et = wid * 2 + k;
    #pragma unroll
    for (int r = 0; r < 4; ++r) {
      int el = (et * 16 + lg * 4 + r) * 17 + lq;
      float v = d2L[el] + d2L[2176 + el] + d2L[4352 + el] + d2L[6528 + el];
      out[(((b << 9) + qt + lq) << 7) + et * 16 + lg * 4 + r] = v;
    }
  }
}

extern "C" void kernel_launch(void* const* d_in, const int* in_sizes, int n_in,
                              void* d_out, int out_size, void* d_ws, size_t ws_size,
                              hipStream_t stream)
{
  const float* q    = (const float*)d_in[0];
  const unsigned char* mask = (const unsigned char*)d_in[1];
  const float* edge = (const float*)d_in[2];
  const float* Wq   = (const float*)d_in[3];
  const float* Wk   = (const float*)d_in[4];
  const float* Wv   = (const float*)d_in[5];
  const float* Wo   = (const float*)d_in[6];
  const float* mW1  = (const float*)d_in[7];
  const float* mb1  = (const float*)d_in[8];
  const float* mW2  = (const float*)d_in[9];
  const float* mb2  = (const float*)d_in[10];
  const float* mW3  = (const float*)d_in[11];
  const float* mb3  = (const float*)d_in[12];
  float* out = (float*)d_out;

  size_t per = (size_t)Hc * Bc * Nc * DKc;     // 2,097,152 bf16 elems per matrix
  short* Wt  = (short*)d_ws;                   // 49152
  short* Wob = Wt + 49152;                     // 16384
  short* Qb  = Wob + 16384;
  short* Kb  = Qb + per;
  short* Vt  = Kb + per;
  int* flag  = (int*)(Vt + per);               // ~12.7 MB used

  hipMemsetAsync(flag, 0, sizeof(int), stream);
  conv_detect<<<dim3(257), dim3(256), 0, stream>>>(Wq, Wk, Wv, Wo, mask, flag, Wt, Wob);
  qkv4<<<dim3(Bc * 32), dim3(256), 0, stream>>>(q, Wt, Qb, Kb, Vt);
  attn5<<<dim3(Bc * 32), dim3(256), 0, stream>>>(edge, mask, flag, Qb, Kb, Vt, Wob,
      mW1, mb1, mW2, mb2, mW3, mb3, out);
}

// Round 6
// 124.240 us; speedup vs baseline: 4.5038x; 1.0467x over previous
//
#include <hip/hip_runtime.h>
#include <hip/hip_bf16.h>
#include <float.h>

#define Bc 32
#define Nc 512
#define Dc 128
#define Hc 8
#define DKc 16
#define Ec 128
#define LOG2E 1.44269504088896340736f
#define SCLAMP 80.0f

typedef __attribute__((ext_vector_type(4))) short s16x4;
typedef __attribute__((ext_vector_type(8))) short s16x8;
typedef __attribute__((ext_vector_type(4))) float f32x4;

union BFU { __hip_bfloat16 b; short s; };
static __device__ inline short f2bf(float f) { BFU u; u.b = __float2bfloat16(f); return u.s; }

// fast f32->bf16 pack: +0x8000 (round-half-up) then v_perm_b32 grabs the two
// high halves. dst = {hi16(b), hi16(a)} with a in the LOW 16 bits (CK idiom).
static __device__ inline unsigned rnd16(float x) { return __float_as_uint(x) + 0x8000u; }
static __device__ inline s16x4 pack4(float a, float b, float c, float d) {
  union { unsigned u[2]; s16x4 v; } r;
  r.u[0] = __builtin_amdgcn_perm(rnd16(b), rnd16(a), 0x07060302u);
  r.u[1] = __builtin_amdgcn_perm(rnd16(d), rnd16(c), 0x07060302u);
  return r.v;
}

#if __has_builtin(__builtin_amdgcn_exp2f)
#define EXP2F(x) __builtin_amdgcn_exp2f(x)
#else
#define EXP2F(x) exp2f(x)
#endif

// D = A*B + C for 16x16x16 bf16. A[m=l&15][k=(l>>4)*4+i]; B[k=(l>>4)*4+i][n=l&15];
// C/D: col(n)=l&15, row(m)=(l>>4)*4+reg.
static __device__ inline f32x4 mfma16(s16x4 a, s16x4 b, f32x4 c) {
#if __has_builtin(__builtin_amdgcn_mfma_f32_16x16x16bf16_1k)
  return __builtin_amdgcn_mfma_f32_16x16x16bf16_1k(a, b, c, 0, 0, 0);
#else
  int lane = threadIdx.x & 63;
  int g = lane >> 4, base = lane & 15;
  int src0 = (base + 32 * g) & 63;
  int src1 = (base + 32 * g + 16) & 63;
  int ax = ((int*)&a)[0], ay = ((int*)&a)[1];
  int bx = ((int*)&b)[0], by = ((int*)&b)[1];
  int A0 = __shfl(ax, src0), A1 = __shfl(ay, src0);
  int A2 = __shfl(ax, src1), A3 = __shfl(ay, src1);
  int B0 = __shfl(bx, src0), B1 = __shfl(by, src0);
  int B2 = __shfl(bx, src1), B3 = __shfl(by, src1);
  if (g >= 2) { A0 = A1 = A2 = A3 = 0; B0 = B1 = B2 = B3 = 0; }
  s16x8 A8, B8;
  ((int*)&A8)[0] = A0; ((int*)&A8)[1] = A1; ((int*)&A8)[2] = A2; ((int*)&A8)[3] = A3;
  ((int*)&B8)[0] = B0; ((int*)&B8)[1] = B1; ((int*)&B8)[2] = B2; ((int*)&B8)[3] = B3;
  return __builtin_amdgcn_mfma_f32_16x16x32_bf16(A8, B8, c, 0, 0, 0);
#endif
}

// ---- prep: weight converter (blocks 0..255) + mask-format detector (block 256) ----
// Wt[mat][h*16+k][d] bf16 (49152) ; Wob[et][s][lane][i] bf16 (16384)
// Detector is single-writer (no memset, no atomics): flag = 1 iff byte-mask.
__global__ __launch_bounds__(256) void prep_kernel(
    const float* __restrict__ Wq, const float* __restrict__ Wk, const float* __restrict__ Wv,
    const float* __restrict__ Wo,
    const unsigned char* __restrict__ m, int* __restrict__ flag,
    short* __restrict__ Wt, short* __restrict__ Wob)
{
  int blk = blockIdx.x;
  int t = threadIdx.x;
  if (blk == 256) {   // detector
    __shared__ int red[4];
    int any = 0;
    for (int u = t; u < 16384; u += 256)
      if ((u & 3) != 0 && m[u] != 0) any = 1;
    unsigned long long bal = __ballot(any != 0);
    if ((t & 63) == 0) red[t >> 6] = (bal != 0ULL) ? 1 : 0;
    __syncthreads();
    if (t == 0) *flag = red[0] | red[1] | red[2] | red[3];
    return;
  }
  int o = blk * 256 + t;
  if (o < 49152) {
    int mat = o >> 14, r = o & 16383;
    int hk = r >> 7, d = r & 127;
    const float* src = (mat == 0) ? Wq : ((mat == 1) ? Wk : Wv);
    Wt[o] = f2bf(src[(hk >> 4) * 2048 + d * 16 + (hk & 15)]);
  } else {
    int o2 = o - 49152;
    int et = o2 >> 11, s = (o2 >> 8) & 7, lane = (o2 >> 2) & 63, i = o2 & 3;
    Wob[o2] = f2bf(Wo[(s * 16 + (lane >> 4) * 4 + i) * 128 + et * 16 + (lane & 15)]);
  }
}

// ---- kernel A: QKV projection via MFMA; 16-row tiles, waves split output col-tiles ----
// Qb (scaled 0.25*log2e), Kb: [h][b][n][16] bf16 ; Vt: [h][b][dv][512] bf16
__global__ __launch_bounds__(256, 4) void qkv4(
    const float* __restrict__ q, const short* __restrict__ Wt,
    short* __restrict__ Qb, short* __restrict__ Kb, short* __restrict__ Vt)
{
  __shared__ short qs[16][136];
  int blk = blockIdx.x;
  int b = blk >> 5;
  int rt = (blk & 31) << 4;
  int t = threadIdx.x;
  int wid = t >> 6, lane = t & 63;
  int lq = lane & 15, lg = lane >> 4;

  #pragma unroll
  for (int it = 0; it < 2; ++it) {
    int u = t + it * 256;
    int row = u >> 5, c4 = (u & 31) << 2;
    float4 v = *(const float4*)&q[((((b << 9) + rt + row) << 7)) + c4];
    *(s16x4*)&qs[row][c4] = pack4(v.x, v.y, v.z, v.w);
  }
  __syncthreads();

  s16x4 af[8];
  #pragma unroll
  for (int ks = 0; ks < 8; ++ks)
    af[ks] = *(const s16x4*)&qs[lq][ks * 16 + lg * 4];

  #pragma unroll 1
  for (int pj = 0; pj < 3; ++pj) {
    const short* Wm = Wt + pj * 16384;
    #pragma unroll
    for (int c2 = 0; c2 < 2; ++c2) {
      int ct = wid * 2 + c2;
      f32x4 acc = (f32x4)0.f;
      #pragma unroll
      for (int ks = 0; ks < 8; ++ks) {
        s16x4 bf = *(const s16x4*)&Wm[(ct * 16 + lq) * 128 + ks * 16 + lg * 4];
        acc = mfma16(af[ks], bf, acc);
      }
      if (pj == 0) {
        s16x4 pk = pack4(acc[0] * (0.25f * LOG2E), acc[1] * (0.25f * LOG2E),
                         acc[2] * (0.25f * LOG2E), acc[3] * (0.25f * LOG2E));
        #pragma unroll
        for (int r = 0; r < 4; ++r)
          Qb[(ct << 18) + (b << 13) + ((rt + lg * 4 + r) << 4) + lq] = pk[r];
      } else if (pj == 1) {
        s16x4 pk = pack4(acc[0], acc[1], acc[2], acc[3]);
        #pragma unroll
        for (int r = 0; r < 4; ++r)
          Kb[(ct << 18) + (b << 13) + ((rt + lg * 4 + r) << 4) + lq] = pk[r];
      } else {
        s16x4 pk = pack4(acc[0], acc[1], acc[2], acc[3]);
        *(s16x4*)&Vt[(ct << 18) + (((b << 4) + lq) << 9) + rt + lg * 4] = pk;
      }
    }
  }
}

// ---- kernel B: fused edge-MLP + masked softmax attention + MFMA out-projection ----
// Block = (b, 16 q-rows); 4 waves each own 8 of the 32 key-chunks (no main-loop barriers).
// LDS: per-wave bf16 bias [8h][16q][20j] (5120B) + etile [16][16] f32 (1024B);
//      epilogue overlay: d2 partials [4][128][17] f32 (34816B) + psum [4][8][16] f32 (2048B).
__global__ __launch_bounds__(256, 4) void attn6(
    const float* __restrict__ edge, const unsigned char* __restrict__ maskB,
    const int* __restrict__ flag,
    const short* __restrict__ Qb, const short* __restrict__ Kb, const short* __restrict__ Vt,
    const short* __restrict__ Wob,
    const float* __restrict__ mW1, const float* __restrict__ mb1,
    const float* __restrict__ mW2, const float* __restrict__ mb2,
    const float* __restrict__ mW3, const float* __restrict__ mb3,
    float* __restrict__ out)
{
  __shared__ __align__(16) char smem[36864];

  int t = threadIdx.x;
  int wid = t >> 6, lane = t & 63;
  int lq = lane & 15, lg = lane >> 4;
  int b = blockIdx.x >> 5;
  int qt = (blockIdx.x & 31) << 4;
  int mflag = *flag;

  short* bias_w = (short*)(smem + wid * 5120);             // [h][q][20]
  float (*etile)[16] = (float(*)[16])(smem + 20480 + wid * 1024);
  float* d2L = (float*)smem;                                // [4][128][17]
  float* psL = (float*)(smem + 34816);                      // [4][8][16]

  // MLP weight fragments (W3/b3 pre-scaled by log2e)
  float W1v[4], b1v[4];
  f32x4 b2v, b3v;
  s16x4 w2f, w3f;
  #pragma unroll
  for (int i = 0; i < 4; ++i) {
    int v = lg * 4 + i;
    W1v[i] = mW1[v];
    b1v[i] = mb1[v];
    b2v[i] = mb2[v];
    b3v[i] = (v < 8) ? mb3[v] * LOG2E : 0.f;
    w2f[i] = f2bf(mW2[v * 16 + lq]);
    w3f[i] = (lq < 8) ? f2bf(mW3[v * 8 + lq] * LOG2E) : (short)0;
  }

  const short* Kl = Kb + (b << 13) + (lq << 4) + (lg << 2);
  const short* Vl = Vt + (((b << 4) + lq) << 9) + (lg << 2);
  const short* Ql = Qb + (b << 13) + ((qt + lq) << 4) + (lg << 2);
  unsigned ebase = (((b << 9) + qt + (lane >> 2)) << 9) + (lane & 3) * 4;
  unsigned mbase = (((b << 9) + qt + lq) << 9) + (lg << 2);

  s16x4 qf[8];
  #pragma unroll
  for (int h = 0; h < 8; ++h) qf[h] = *(const s16x4*)(Ql + (h << 18));

  f32x4 oacc[8];
  float psum[8];
  #pragma unroll
  for (int h = 0; h < 8; ++h) { oacc[h] = (f32x4)0.f; psum[h] = 0.f; }

  // prologue: this wave's chunk 0
  int jb = wid << 4;
  float4 ev = *(const float4*)&edge[ebase + jb];
  int4 mkv;
  if (mflag) {
    uchar4 u = *(const uchar4*)&maskB[mbase + jb];
    mkv.x = u.x; mkv.y = u.y; mkv.z = u.z; mkv.w = u.w;
  } else {
    mkv = *(const int4*)&((const int*)maskB)[mbase + jb];
  }

  #pragma unroll 1
  for (int cc = 0; cc < 8; ++cc) {
    jb = ((cc << 2) | wid) << 4;
    *(float4*)&etile[lane >> 2][(lane & 3) * 4] = ev;

    float4 evn; int4 mkn;
    if (cc < 7) {
      int jbn = (((cc + 1) << 2) | wid) << 4;
      evn = *(const float4*)&edge[ebase + jbn];
      if (mflag) {
        uchar4 u = *(const uchar4*)&maskB[mbase + jbn];
        mkn.x = u.x; mkn.y = u.y; mkn.z = u.z; mkn.w = u.w;
      } else {
        mkn = *(const int4*)&((const int*)maskB)[mbase + jbn];
      }
    } else { evn = ev; mkn = mkv; }

    s16x4 kf[8];
    #pragma unroll
    for (int h = 0; h < 8; ++h) kf[h] = *(const s16x4*)(Kl + (h << 18) + (jb << 4));

    // edge MLP; bias (log2e-scaled) -> bf16 LDS [h][q][j]
    #pragma unroll 4
    for (int qq = 0; qq < 16; ++qq) {
      float e = etile[qq][lq];
      s16x4 h1f = pack4(fmaxf(0.f, fmaf(e, W1v[0], b1v[0])),
                        fmaxf(0.f, fmaf(e, W1v[1], b1v[1])),
                        fmaxf(0.f, fmaf(e, W1v[2], b1v[2])),
                        fmaxf(0.f, fmaf(e, W1v[3], b1v[3])));
      f32x4 c2 = mfma16(w2f, h1f, b2v);
      s16x4 rf = pack4(fmaxf(c2[0], 0.f), fmaxf(c2[1], 0.f),
                       fmaxf(c2[2], 0.f), fmaxf(c2[3], 0.f));
      f32x4 c3 = mfma16(w3f, rf, b3v);
      if (lg < 2) {
        s16x4 pk = pack4(c3[0], c3[1], c3[2], c3[3]);
        #pragma unroll
        for (int r = 0; r < 4; ++r)
          bias_w[(lg * 4 + r) * 320 + qq * 20 + lq] = pk[r];
      }
    }

    // per-head: S^T = K.Q^T + bias' ; p = exp2(min(sc,80)) ; O^T += V^T.P^T
    #pragma unroll
    for (int h = 0; h < 8; ++h) {
      union { s16x4 v; int i[2]; } bb;
      bb.v = *(const s16x4*)&bias_w[h * 320 + lq * 20 + lg * 4];
      f32x4 sc;
      sc[0] = __int_as_float(bb.i[0] << 16);
      sc[1] = __int_as_float(bb.i[0] & 0xffff0000);
      sc[2] = __int_as_float(bb.i[1] << 16);
      sc[3] = __int_as_float(bb.i[1] & 0xffff0000);
      sc = mfma16(kf[h], qf[h], sc);
      s16x4 vf = *(const s16x4*)(Vl + (h << 18) + jb);
      float p0 = mkv.x ? 0.f : EXP2F(fminf(sc[0], SCLAMP));
      float p1 = mkv.y ? 0.f : EXP2F(fminf(sc[1], SCLAMP));
      float p2 = mkv.z ? 0.f : EXP2F(fminf(sc[2], SCLAMP));
      float p3 = mkv.w ? 0.f : EXP2F(fminf(sc[3], SCLAMP));
      psum[h] += (p0 + p1) + (p2 + p3);
      s16x4 pf = pack4(p0, p1, p2, p3);
      oacc[h] = mfma16(vf, pf, oacc[h]);
    }
    ev = evn; mkv = mkn;
  }

  // ---- epilogue: cross-wave psum, normalize, MFMA out-projection, merge ----
  #pragma unroll
  for (int h = 0; h < 8; ++h) {
    float s = psum[h];
    s += __shfl_xor(s, 16);
    s += __shfl_xor(s, 32);
    psum[h] = s;
  }
  if (lg == 0) {
    #pragma unroll
    for (int h = 0; h < 8; ++h) psL[wid * 128 + h * 16 + lq] = psum[h];
  }
  __syncthreads();

  s16x4 obf[8];
  #pragma unroll
  for (int h = 0; h < 8; ++h) {
    float tot = psL[h * 16 + lq] + psL[128 + h * 16 + lq]
              + psL[256 + h * 16 + lq] + psL[384 + h * 16 + lq];
    float inv = (tot > 0.f) ? 1.f / tot : 0.f;
    obf[h] = pack4(oacc[h][0] * inv, oacc[h][1] * inv, oacc[h][2] * inv, oacc[h][3] * inv);
  }

  f32x4 d2a[8];
  #pragma unroll
  for (int et = 0; et < 8; ++et) d2a[et] = (f32x4)0.f;
  #pragma unroll
  for (int s = 0; s < 8; ++s) {
    #pragma unroll
    for (int et = 0; et < 8; ++et) {
      s16x4 wo = *(const s16x4*)&Wob[((et * 8 + s) << 8) + (lane << 2)];
      d2a[et] = mfma16(wo, obf[s], d2a[et]);
    }
  }

  // write partials (overlay region; all waves past their bias reads via barrier above)
  #pragma unroll
  for (int et = 0; et < 8; ++et)
    #pragma unroll
    for (int r = 0; r < 4; ++r)
      d2L[(wid * 128 + et * 16 + lg * 4 + r) * 17 + lq] = d2a[et][r];
  __syncthreads();

  // merge: wave w handles e-tiles {2w, 2w+1}
  #pragma unroll
  for (int k = 0; k < 2; ++k) {
    int et = wid * 2 + k;
    #pragma unroll
    for (int r = 0; r < 4; ++r) {
      int el = (et * 16 + lg * 4 + r) * 17 + lq;
      float v = d2L[el] + d2L[2176 + el] + d2L[4352 + el] + d2L[6528 + el];
      out[(((b << 9) + qt + lq) << 7) + et * 16 + lg * 4 + r] = v;
    }
  }
}

extern "C" void kernel_launch(void* const* d_in, const int* in_sizes, int n_in,
                              void* d_out, int out_size, void* d_ws, size_t ws_size,
                              hipStream_t stream)
{
  const float* q    = (const float*)d_in[0];
  const unsigned char* mask = (const unsigned char*)d_in[1];
  const float* edge = (const float*)d_in[2];
  const float* Wq   = (const float*)d_in[3];
  const float* Wk   = (const float*)d_in[4];
  const float* Wv   = (const float*)d_in[5];
  const float* Wo   = (const float*)d_in[6];
  const float* mW1  = (const float*)d_in[7];
  const float* mb1  = (const float*)d_in[8];
  const float* mW2  = (const float*)d_in[9];
  const float* mb2  = (const float*)d_in[10];
  const float* mW3  = (const float*)d_in[11];
  const float* mb3  = (const float*)d_in[12];
  float* out = (float*)d_out;

  size_t per = (size_t)Hc * Bc * Nc * DKc;     // 2,097,152 bf16 elems per matrix
  short* Wt  = (short*)d_ws;                   // 49152
  short* Wob = Wt + 49152;                     // 16384
  short* Qb  = Wob + 16384;
  short* Kb  = Qb + per;
  short* Vt  = Kb + per;
  int* flag  = (int*)(Vt + per);               // ~12.7 MB used

  prep_kernel<<<dim3(257), dim3(256), 0, stream>>>(Wq, Wk, Wv, Wo, mask, flag, Wt, Wob);
  qkv4<<<dim3(Bc * 32), dim3(256), 0, stream>>>(q, Wt, Qb, Kb, Vt);
  attn6<<<dim3(Bc * 32), dim3(256), 0, stream>>>(edge, mask, flag, Qb, Kb, Vt, Wob,
      mW1, mb1, mW2, mb2, mW3, mb3, out);
}